// Round 6
// baseline (602.962 us; speedup 1.0000x reference)
//
#include <hip/hip_runtime.h>
#include <hip/hip_bf16.h>
#include <stdint.h>

// Problem constants
#define E_NUM 8
#define D_DIM 512
#define H_DIM 2048
#define NTOK 16384   // B*S = 8*2048

typedef __bf16 bf16;
typedef __bf16 bf16x8 __attribute__((ext_vector_type(8)));
typedef float  f32x4  __attribute__((ext_vector_type(4)));

#define BM 128
#define BN 128
#define BK 64
#define KSPLIT 2     // gemm2 K-split: breaks the barrier convoy via TLP (more resident blocks)

// async global->LDS, 16B per lane
typedef __attribute__((address_space(1))) const void* gas_cp;
typedef __attribute__((address_space(3))) void* las_p;
__device__ __forceinline__ void gl_lds16(const void* g, void* l) {
  __builtin_amdgcn_global_load_lds((gas_cp)g, (las_p)l, 16, 0, 0);
}

// Workspace layout (bytes)
static const size_t OFF_FILL = 32;           // 8 ints (per-expert count after fill)
static const size_t OFF_LIST = 128;          // E*NTOK ints = 512KB
static const size_t OFF_XBF  = 1ull << 20;                              // bf16 [NTOK][D] = 16.8MB
static const size_t OFF_W1T  = OFF_XBF + (size_t)NTOK*D_DIM*2;          // bf16 [E][H][D]
static const size_t OFF_W2T  = OFF_W1T + (size_t)E_NUM*H_DIM*D_DIM*2;   // bf16 [E][D][H]
static const size_t OFF_HBUF = OFF_W2T + (size_t)E_NUM*H_DIM*D_DIM*2;   // bf16 [<=33792][H]

// rowbase for expert e, computed from counts (all blocks agree; cnt final at kernel launch)
__device__ __forceinline__ int rowbase_of(const int* cnt, int e) {
  int acc = 0;
  for (int i = 0; i < e; i++) acc += (cnt[i] + BM - 1) & ~(BM - 1);
  return acc;
}

// ---------------- routing: fill lists + counts in one kernel ----------------
__global__ void fill_kernel(const int* __restrict__ assign, int* __restrict__ fill,
                            int* __restrict__ lists) {
  int n = blockIdx.x * blockDim.x + threadIdx.x;
  if (n >= NTOK) return;
  int e0 = assign[2*n], e1 = assign[2*n+1];
  int p0 = atomicAdd(&fill[e0], 1);
  lists[e0 * NTOK + p0] = n;
  if (e1 != e0) {
    int p1 = atomicAdd(&fill[e1], 1);
    lists[e1 * NTOK + p1] = n;
  }
}

// ---------------- fused prep: cvt_x + W1 transpose + W2 transpose ----------------
// job layout (blockIdx.x): [0,4096) cvt_x; [4096,12288) W1T; [12288,20480) W2T
#define NB_CVT 4096
#define NB_W1  8192   // (2048/32)*(512/32)*8
#define NB_W2  8192   // (512/32)*(2048/32)*8

__device__ __forceinline__ void tr_tile(const float* __restrict__ src, bf16* __restrict__ dst,
                                        int R, int C, int r0, int c0, int tid) {
  __shared__ float tile[32][33];
  int tx = tid & 31, ty = tid >> 5;  // 32 x 8
  #pragma unroll
  for (int i = 0; i < 32; i += 8)
    tile[ty + i][tx] = src[(size_t)(r0 + ty + i) * C + c0 + tx];
  __syncthreads();
  #pragma unroll
  for (int i = 0; i < 32; i += 8)
    dst[(size_t)(c0 + ty + i) * R + r0 + tx] = (bf16)tile[tx][ty + i];
}

__global__ __launch_bounds__(256) void prep(
    const float* __restrict__ x, const float* __restrict__ W1, const float* __restrict__ W2,
    bf16* __restrict__ xbf, bf16* __restrict__ w1t, bf16* __restrict__ w2t) {
  int bid = blockIdx.x;
  int tid = threadIdx.x;
  if (bid < NB_CVT) {
    size_t i = (size_t)bid * 2048 + (size_t)tid * 8;
    float4 a = *reinterpret_cast<const float4*>(x + i);
    float4 b = *reinterpret_cast<const float4*>(x + i + 4);
    bf16x8 o;
    o[0] = (bf16)a.x; o[1] = (bf16)a.y; o[2] = (bf16)a.z; o[3] = (bf16)a.w;
    o[4] = (bf16)b.x; o[5] = (bf16)b.y; o[6] = (bf16)b.z; o[7] = (bf16)b.w;
    *reinterpret_cast<bf16x8*>(xbf + i) = o;
  } else if (bid < NB_CVT + NB_W1) {
    // W1 [E][512][2048] -> w1t [E][2048][512]; R=512, C=2048
    int b = bid - NB_CVT;
    int e = b >> 10;                 // / (64*16)
    int r = b & 1023;
    int cx = r & 63, ry = r >> 6;
    tr_tile(W1 + (size_t)e * D_DIM * H_DIM, w1t + (size_t)e * D_DIM * H_DIM,
            D_DIM, H_DIM, ry * 32, cx * 32, tid);
  } else {
    // W2 [E][2048][512] -> w2t [E][512][2048]; R=2048, C=512
    int b = bid - NB_CVT - NB_W1;
    int e = b >> 10;
    int r = b & 1023;
    int cx = r & 15, ry = r >> 4;
    tr_tile(W2 + (size_t)e * D_DIM * H_DIM, w2t + (size_t)e * D_DIM * H_DIM,
            H_DIM, D_DIM, ry * 32, cx * 32, tid);
  }
}

// ---------------- GEMM1: h = relu(Xg @ W1 + b1), bf16 out to hbuf ----------------
// grid: 1D, lin = xcd + 8*(nc + NC1*rbHi); rb = rbHi*8 + xcd; NC1 = 16 chunks over H
#define NC1 (H_DIM / BN)   // 16
__global__ __launch_bounds__(256) void gemm1(
    const bf16* __restrict__ xbf, const bf16* __restrict__ w1t,
    const float* __restrict__ b1, const int* __restrict__ lists,
    const int* __restrict__ cnt, bf16* __restrict__ hbuf) {
  int lin = blockIdx.x;
  int xcd = lin & 7;
  int rem = lin >> 3;
  int nc  = rem & (NC1 - 1);
  int rb  = (rem >> 4) * 8 + xcd;
  int e   = rb >> 7;
  int m0  = (rb & 127) * BM;
  int ce  = cnt[e];
  if (m0 >= ce) return;
  int n0 = nc * BN;
  int rbase = rowbase_of(cnt, e);

  __shared__ bf16 xs[2][BM * BK];   // double-buffered (r3: measured best for gemm1)
  __shared__ bf16 bs[2][BN * BK];
  __shared__ int tok[BM];

  int tid = threadIdx.x;
  if (tid < BM) {
    int r = m0 + tid;
    tok[tid] = (r < ce) ? lists[e * NTOK + r] : lists[e * NTOK];
  }
  __syncthreads();

  const bf16* w1e = w1t + (size_t)e * H_DIM * D_DIM + (size_t)n0 * D_DIM;
  int wave = tid >> 6, lane = tid & 63;
  int quad = lane >> 4, l16 = lane & 15;
  int lr = lane >> 3, lc = (lane & 7) * 8;
  int wm = (wave & 1) * 64, wn = (wave >> 1) * 64;
  f32x4 acc[4][4] = {};

  auto stage = [&](int buf, int k0) {
    #pragma unroll
    for (int i = 0; i < 4; i++) {
      int s = wave * 4 + i;
      int t = tok[s * 8 + lr];
      gl_lds16(xbf + (size_t)t * D_DIM + k0 + lc, &xs[buf][s * 512]);
    }
    #pragma unroll
    for (int i = 0; i < 4; i++) {
      int s = wave * 4 + i;
      gl_lds16(w1e + (size_t)(s * 8 + lr) * D_DIM + k0 + lc, &bs[buf][s * 512]);
    }
  };

  const int nk = D_DIM / BK;  // 8
  stage(0, 0);
  for (int ki = 0; ki < nk; ki++) {
    __syncthreads();
    if (ki + 1 < nk) stage((ki + 1) & 1, (ki + 1) * BK);
    const bf16* xsc = xs[ki & 1];
    const bf16* bsc = bs[ki & 1];
    #pragma unroll
    for (int kk = 0; kk < BK; kk += 32) {
      bf16x8 af[4], bfr[4];
      #pragma unroll
      for (int i = 0; i < 4; i++)
        af[i] = *reinterpret_cast<const bf16x8*>(&xsc[(wm + i * 16 + l16) * BK + kk + quad * 8]);
      #pragma unroll
      for (int j = 0; j < 4; j++)
        bfr[j] = *reinterpret_cast<const bf16x8*>(&bsc[(wn + j * 16 + l16) * BK + kk + quad * 8]);
      #pragma unroll
      for (int i = 0; i < 4; i++)
        #pragma unroll
        for (int j = 0; j < 4; j++)
          acc[i][j] = __builtin_amdgcn_mfma_f32_16x16x32_bf16(af[i], bfr[j], acc[i][j], 0, 0, 0);
    }
  }

  bf16* hrow = hbuf + (size_t)(rbase + m0) * H_DIM;
  #pragma unroll
  for (int i = 0; i < 4; i++) {
    int row = wm + i * 16 + quad * 4;
    #pragma unroll
    for (int j = 0; j < 4; j++) {
      int col = n0 + wn + j * 16 + l16;
      float bias = b1[e * H_DIM + col];
      #pragma unroll
      for (int r = 0; r < 4; r++) {
        float v = acc[i][j][r] + bias;
        v = v > 0.f ? v : 0.f;
        hrow[(size_t)(row + r) * H_DIM + col] = (bf16)v;
      }
    }
  }
}

// ---------------- GEMM2: out += 0.5*(h @ W2 + b2), K-split x2, fp32 atomicAdd ----------------
#define NC2 (D_DIM / BN)   // 4
__global__ __launch_bounds__(256) void gemm2(
    const bf16* __restrict__ hbuf, const bf16* __restrict__ w2t,
    const float* __restrict__ b2, const int* __restrict__ lists,
    const int* __restrict__ cnt, float* __restrict__ out) {
  int lin = blockIdx.x;
  int xcd = lin & 7;
  int rem = lin >> 3;
  int nc  = rem & (NC2 - 1);
  int rem2 = rem >> 2;
  int ks  = rem2 & (KSPLIT - 1);
  int rb  = (rem2 >> 1) * 8 + xcd;     // rem2 >> log2(KSPLIT)
  int e   = rb >> 7;
  int m0  = (rb & 127) * BM;
  int ce  = cnt[e];
  if (m0 >= ce) return;
  int n0 = nc * BN;
  int rbase = rowbase_of(cnt, e);
  const int kbase = ks * (H_DIM / KSPLIT);   // 0 or 1024
  const int kend  = kbase + H_DIM / KSPLIT;

  __shared__ bf16 hs[BM * BK];
  __shared__ bf16 bs[BN * BK];
  __shared__ int tok[BM];

  int tid = threadIdx.x;
  if (tid < BM) {
    int r = m0 + tid;
    tok[tid] = (r < ce) ? lists[e * NTOK + r] : -1;
  }
  __syncthreads();

  const bf16* hbase = hbuf + (size_t)(rbase + m0) * H_DIM;
  const bf16* w2e = w2t + (size_t)e * H_DIM * D_DIM + (size_t)n0 * H_DIM;
  int wave = tid >> 6, lane = tid & 63;
  int quad = lane >> 4, l16 = lane & 15;
  int lr = lane >> 3, lc = (lane & 7) * 8;
  int wm = (wave & 1) * 64, wn = (wave >> 1) * 64;
  f32x4 acc[4][4] = {};

  for (int k0 = kbase; k0 < kend; k0 += BK) {
    #pragma unroll
    for (int i = 0; i < 4; i++) {
      int s = wave * 4 + i;
      gl_lds16(hbase + (size_t)(s * 8 + lr) * H_DIM + k0 + lc, &hs[s * 512]);
    }
    #pragma unroll
    for (int i = 0; i < 4; i++) {
      int s = wave * 4 + i;
      gl_lds16(w2e + (size_t)(s * 8 + lr) * H_DIM + k0 + lc, &bs[s * 512]);
    }
    __syncthreads();
    #pragma unroll
    for (int kk = 0; kk < BK; kk += 32) {
      bf16x8 af[4], bfr[4];
      #pragma unroll
      for (int i = 0; i < 4; i++)
        af[i] = *reinterpret_cast<const bf16x8*>(&hs[(wm + i * 16 + l16) * BK + kk + quad * 8]);
      #pragma unroll
      for (int j = 0; j < 4; j++)
        bfr[j] = *reinterpret_cast<const bf16x8*>(&bs[(wn + j * 16 + l16) * BK + kk + quad * 8]);
      #pragma unroll
      for (int i = 0; i < 4; i++)
        #pragma unroll
        for (int j = 0; j < 4; j++)
          acc[i][j] = __builtin_amdgcn_mfma_f32_16x16x32_bf16(af[i], bfr[j], acc[i][j], 0, 0, 0);
    }
    __syncthreads();
  }

  #pragma unroll
  for (int i = 0; i < 4; i++) {
    int row = wm + i * 16 + quad * 4;
    #pragma unroll
    for (int j = 0; j < 4; j++) {
      int col = n0 + wn + j * 16 + l16;
      float bb = (ks == 0) ? b2[e * D_DIM + col] : 0.f;   // bias once per output
      #pragma unroll
      for (int r = 0; r < 4; r++) {
        int t = tok[row + r];
        if (t >= 0) {
          float v = 0.5f * (acc[i][j][r] + bb);
          atomicAdd(&out[(size_t)t * D_DIM + col], v);
        }
      }
    }
  }
}

// ---------------- launch ----------------
extern "C" void kernel_launch(void* const* d_in, const int* in_sizes, int n_in,
                              void* d_out, int out_size, void* d_ws, size_t ws_size,
                              hipStream_t stream) {
  const float* x      = (const float*)d_in[0];
  const int*   assign = (const int*)d_in[1];
  const float* W1     = (const float*)d_in[2];
  const float* b1     = (const float*)d_in[3];
  const float* W2     = (const float*)d_in[4];
  const float* b2     = (const float*)d_in[5];
  float* out = (float*)d_out;
  char* ws = (char*)d_ws;

  int* fill    = (int*)(ws + OFF_FILL);
  int* lists   = (int*)(ws + OFF_LIST);
  bf16* xbf    = (bf16*)(ws + OFF_XBF);
  bf16* w1t    = (bf16*)(ws + OFF_W1T);
  bf16* w2t    = (bf16*)(ws + OFF_W2T);
  bf16* hbuf   = (bf16*)(ws + OFF_HBUF);

  hipMemsetAsync(ws, 0, 128, stream);
  hipMemsetAsync(d_out, 0, (size_t)out_size * sizeof(float), stream);

  fill_kernel<<<NTOK / 256, 256, 0, stream>>>(assign, fill, lists);
  prep<<<NB_CVT + NB_W1 + NB_W2, 256, 0, stream>>>(x, W1, W2, xbf, w1t, w2t);

  gemm1<<<(E_NUM * NTOK / BM) * NC1, 256, 0, stream>>>(xbf, w1t, b1, lists, fill, hbuf);
  gemm2<<<(E_NUM * NTOK / BM) * NC2 * KSPLIT, 256, 0, stream>>>(hbuf, w2t, b2, lists, fill, out);

  (void)in_sizes; (void)n_in; (void)ws_size;
}